// Round 3
// baseline (537.112 us; speedup 1.0000x reference)
//
#include <hip/hip_runtime.h>
#include <hip/hip_bf16.h>

// B=16, S=2048, D=64 attention w/ symmetric pad mask.
// out = [context (B*S*D fp32), attn (B*S*S fp32)] concatenated.
//
// R3 = R2 design (two-pass recompute, 16x256 LDS panel) with the attn-write
// index fix: panel is 16 rows x 64 float4/row -> i = idx>>6, j4 = (idx&63)*4.
// R2's idx>>5 wrote rows 16..31 past the tile -> OOB fault on the last tile.
#define NBATCH 16
#define SLEN   2048
#define DIM    64
#define TQ     16      // query rows per block
#define NWAVE  8
#define NTHR   512
#define PANEL  256
#define NPANEL (SLEN / PANEL)   // 8
#define PROW   (PANEL + 4)      // +4 floats: row stride 4 banks apart

typedef __attribute__((ext_vector_type(8))) short bf16x8;
typedef __attribute__((ext_vector_type(4))) float f32x4;

__device__ inline short f2bf(float f) {
    union { __hip_bfloat16 h; short s; } u;
    u.h = __float2bfloat16(f);
    return u.s;
}

__device__ inline bf16x8 pack8(float4 a, float4 b) {
    bf16x8 r;
    r[0] = f2bf(a.x); r[1] = f2bf(a.y); r[2] = f2bf(a.z); r[3] = f2bf(a.w);
    r[4] = f2bf(b.x); r[5] = f2bf(b.y); r[6] = f2bf(b.z); r[7] = f2bf(b.w);
    return r;
}

__global__ __launch_bounds__(NTHR, 6) void sdpa_kernel(
    const float* __restrict__ Q, const float* __restrict__ K,
    const float* __restrict__ V, const int* __restrict__ M,
    float* __restrict__ outCtx, float* __restrict__ outAttn)
{
    __shared__ float sPanel[TQ * PROW];      // 16.6 KB normalized attn panel
    __shared__ float emult[SLEN];            // 8 KB 0/1 column mask
    __shared__ float partial[NWAVE * TQ];    // cross-wave row-sum partials
    __shared__ float scalev[TQ];             // 1/l (0 for masked rows)
    __shared__ float ctxpart[2 * TQ * DIM];  // 8 KB split-K PV partials

    const int tid = threadIdx.x;
    const int w   = tid >> 6;      // wave 0..7
    const int l   = tid & 63;
    const int g   = l >> 4;        // quad group 0..3
    const int c   = l & 15;

    const int b  = blockIdx.x >> 7;      // batch (128 tiles/batch)
    const int qt = blockIdx.x & 127;
    const int i0 = qt * TQ;

    const float* Qb = Q + ((size_t)b * SLEN + i0) * DIM;
    const float* Kb = K + (size_t)b * SLEN * DIM;
    const float* Vb = V + (size_t)b * SLEN * DIM;
    const int*   Mb = M + b * SLEN;

    for (int j = tid; j < SLEN; j += NTHR)
        emult[j] = Mb[j] ? 0.0f : 1.0f;

    // Q A-fragments: lane holds Q[i0 + c][g*8 + 0..7] (and +32 for k=32..63)
    bf16x8 qa0, qa1;
    {
        const float* qp = Qb + (size_t)c * DIM + g * 8;
        qa0 = pack8(*(const float4*)(qp),      *(const float4*)(qp + 4));
        qa1 = pack8(*(const float4*)(qp + 32), *(const float4*)(qp + 36));
    }
    __syncthreads();

    const float scl = 0.125f;   // 1/sqrt(64)

    // ---- Pass A: row sums (no staging) ----
    float rsum[4] = {0.f, 0.f, 0.f, 0.f};
    for (int jt = w; jt < SLEN / 16; jt += NWAVE) {
        const int j0 = jt * 16;
        const float* kp = Kb + (size_t)(j0 + c) * DIM + g * 8;
        bf16x8 kb0 = pack8(*(const float4*)(kp),      *(const float4*)(kp + 4));
        bf16x8 kb1 = pack8(*(const float4*)(kp + 32), *(const float4*)(kp + 36));
        f32x4 acc = {0.f, 0.f, 0.f, 0.f};
        acc = __builtin_amdgcn_mfma_f32_16x16x32_bf16(qa0, kb0, acc, 0, 0, 0);
        acc = __builtin_amdgcn_mfma_f32_16x16x32_bf16(qa1, kb1, acc, 0, 0, 0);
        const float em = emult[j0 + c];
        #pragma unroll
        for (int r = 0; r < 4; r++)
            rsum[r] += __expf(acc[r] * scl) * em;
    }
    #pragma unroll
    for (int off = 1; off < 16; off <<= 1) {
        #pragma unroll
        for (int r = 0; r < 4; r++)
            rsum[r] += __shfl_xor(rsum[r], off, 64);
    }
    if (c == 0) {
        #pragma unroll
        for (int r = 0; r < 4; r++)
            partial[w * TQ + g * 4 + r] = rsum[r];
    }
    __syncthreads();
    if (tid < TQ) {
        float lsum = 0.f;
        #pragma unroll
        for (int ww = 0; ww < NWAVE; ww++) lsum += partial[ww * TQ + tid];
        const int rowm = Mb[i0 + tid];
        scalev[tid] = (rowm || lsum <= 0.f) ? 0.f : 1.f / lsum;
    }
    __syncthreads();

    float scv[4];
    #pragma unroll
    for (int r = 0; r < 4; r++) scv[r] = scalev[g * 4 + r];

    // ---- Pass B: recompute per panel, write attn, accumulate PV ----
    const int nt = w & 3, kh = w >> 2;   // PV wave roles: n-tile, k-half
    const int n0 = nt * 16;
    f32x4 pvacc = {0.f, 0.f, 0.f, 0.f};
    const size_t attnBase = ((size_t)b * SLEN + i0) * SLEN;

    for (int p = 0; p < NPANEL; p++) {
        // recompute 16 tiles (2 per wave), store NORMALIZED attn into sPanel
        #pragma unroll
        for (int tt = 0; tt < 2; tt++) {
            const int jloc = (w * 2 + tt) * 16;
            const int j0 = p * PANEL + jloc;
            const float* kp = Kb + (size_t)(j0 + c) * DIM + g * 8;
            bf16x8 kb0 = pack8(*(const float4*)(kp),      *(const float4*)(kp + 4));
            bf16x8 kb1 = pack8(*(const float4*)(kp + 32), *(const float4*)(kp + 36));
            f32x4 acc = {0.f, 0.f, 0.f, 0.f};
            acc = __builtin_amdgcn_mfma_f32_16x16x32_bf16(qa0, kb0, acc, 0, 0, 0);
            acc = __builtin_amdgcn_mfma_f32_16x16x32_bf16(qa1, kb1, acc, 0, 0, 0);
            const float em = emult[j0 + c];
            #pragma unroll
            for (int r = 0; r < 4; r++)
                sPanel[(g * 4 + r) * PROW + jloc + c] =
                    __expf(acc[r] * scl) * em * scv[r];
        }
        __syncthreads();

        // coalesced attn write: 16 rows x 64 float4 = 1024 float4s, 512 thr
        #pragma unroll
        for (int t = 0; t < 2; t++) {
            const int idx = tid + t * NTHR;
            const int i = idx >> 6, j4 = (idx & 63) * 4;
            float4 v = *(const float4*)(sPanel + i * PROW + j4);
            *(float4*)(outAttn + attnBase + (size_t)i * SLEN + p * PANEL + j4) = v;
        }

        // PV: wave (kh,nt) accumulates k-range [kh*128, kh*128+128) of panel
        #pragma unroll
        for (int ks = 0; ks < PANEL / 64; ks++) {   // 4 steps of 32
            const int kloc = kh * (PANEL / 2) + ks * 32;
            const int kb = p * PANEL + kloc;
            const float* pp = sPanel + c * PROW + kloc + g * 8;
            bf16x8 af = pack8(*(const float4*)(pp), *(const float4*)(pp + 4));
            const float* vp = Vb + (size_t)(kb + g * 8) * DIM + n0 + c;
            bf16x8 bfr;
            #pragma unroll
            for (int jj = 0; jj < 8; jj++) bfr[jj] = f2bf(vp[(size_t)jj * DIM]);
            pvacc = __builtin_amdgcn_mfma_f32_16x16x32_bf16(af, bfr, pvacc, 0, 0, 0);
        }
        __syncthreads();   // before next panel overwrites sPanel
    }

    // combine split-K halves (P was pre-normalized; no further scaling)
    #pragma unroll
    for (int r = 0; r < 4; r++)
        ctxpart[(kh * TQ + g * 4 + r) * DIM + n0 + c] = pvacc[r];
    __syncthreads();
    #pragma unroll
    for (int t = 0; t < 2; t++) {
        const int idx = tid + t * NTHR;   // TQ*DIM = 1024
        const int i = idx >> 6, n = idx & 63;
        outCtx[((size_t)b * SLEN + i0 + i) * DIM + n] =
            ctxpart[i * DIM + n] + ctxpart[(TQ + i) * DIM + n];
    }
}

extern "C" void kernel_launch(void* const* d_in, const int* in_sizes, int n_in,
                              void* d_out, int out_size, void* d_ws, size_t ws_size,
                              hipStream_t stream) {
    const float* Q = (const float*)d_in[0];
    const float* K = (const float*)d_in[1];
    const float* V = (const float*)d_in[2];
    const int*   M = (const int*)d_in[3];
    float* outCtx  = (float*)d_out;
    float* outAttn = (float*)d_out + (size_t)NBATCH * SLEN * DIM;
    dim3 grid(NBATCH * (SLEN / TQ));   // 2048 blocks
    sdpa_kernel<<<grid, NTHR, 0, stream>>>(Q, K, V, M, outCtx, outAttn);
}

// Round 4
// 374.936 us; speedup vs baseline: 1.4325x; 1.4325x over previous
//
#include <hip/hip_runtime.h>
#include <hip/hip_bf16.h>

// B=16, S=2048, D=64 attention w/ symmetric pad mask.
// out = [context (B*S*D fp32), attn (B*S*S fp32)] concatenated.
//
// R4: L2-traffic fix. R1/R3 were L2-bound: 2048 blocks x (K twice + V once)
// = 3.1 GB L2 reads vs 380 MB HBM. Now TQ=64 (4 waves, one 16-row q-tile per
// wave, fully wave-independent softmax state), K/V^T staged in LDS once per
// block per panel -> 768 MB L2. V^T staged with XOR swizzle so PV B-frags are
// single ds_read_b128 (replaces R3's 8 scalar global loads per frag).
// P panel staged bf16 per-wave: feeds coalesced fp32 attn writes AND direct
// b128 A-frags for PV. LDS 52.5 KB -> 3 blocks/CU.
#define NBATCH 16
#define SLEN   2048
#define DIM    64
#define TQ     64
#define NTHR   256
#define NW     4
#define PANEL  128
#define NPANEL (SLEN / PANEL)   // 16
#define PROWK  72               // shorts: 64 data + 8 pad (row stride mult of 16 B)
#define PROWV  136              // shorts: 128 data + 8 pad
#define PROWP  136              // shorts: 128 data + 8 pad

typedef __attribute__((ext_vector_type(8))) short bf16x8;
typedef __attribute__((ext_vector_type(4))) float f32x4;

__device__ inline short f2bf(float f) {
    union { __hip_bfloat16 h; short s; } u;
    u.h = __float2bfloat16(f);
    return u.s;
}
__device__ inline float bf2f(unsigned short s) {
    union { unsigned u; float f; } x;
    x.u = ((unsigned)s) << 16;
    return x.f;
}
__device__ inline bf16x8 pack8(float4 a, float4 b) {
    bf16x8 r;
    r[0] = f2bf(a.x); r[1] = f2bf(a.y); r[2] = f2bf(a.z); r[3] = f2bf(a.w);
    r[4] = f2bf(b.x); r[5] = f2bf(b.y); r[6] = f2bf(b.z); r[7] = f2bf(b.w);
    return r;
}

__global__ __launch_bounds__(NTHR, 3) void sdpa_kernel(
    const float* __restrict__ Q, const float* __restrict__ K,
    const float* __restrict__ V, const int* __restrict__ M,
    float* __restrict__ outCtx, float* __restrict__ outAttn)
{
    __shared__ __align__(16) short sK[128 * PROWK];   // K panel bf16 [k][d], 18.0 KB
    __shared__ __align__(16) short sVT[64 * PROWV];   // V^T bf16 [d][k^swz], 17.0 KB
    __shared__ __align__(16) short sP[NW * 16 * PROWP]; // per-wave P bf16, 17.0 KB
    __shared__ float sMask[PANEL];                    // 0/1 column mask, 0.5 KB

    const int tid = threadIdx.x;
    const int w = tid >> 6, l = tid & 63, g = l >> 4, c = l & 15;
    const int b  = blockIdx.x >> 5;          // 32 blocks/batch
    const int i0 = (blockIdx.x & 31) * TQ;
    const int i0w = i0 + w * 16;             // this wave's q-row base

    const float* Kb = K + (size_t)b * SLEN * DIM;
    const float* Vb = V + (size_t)b * SLEN * DIM;
    const int*   Mb = M + b * SLEN;

    // Q A-frags: lane (g,c) holds Q[i0w + c][g*8 .. +7] (and +32)
    bf16x8 qa0, qa1;
    {
        const float* qp = Q + ((size_t)b * SLEN + i0w + c) * DIM + g * 8;
        qa0 = pack8(*(const float4*)(qp),      *(const float4*)(qp + 4));
        qa1 = pack8(*(const float4*)(qp + 32), *(const float4*)(qp + 36));
    }

    const float scl = 0.125f;   // 1/sqrt(64)
    float rsum[4] = {0.f, 0.f, 0.f, 0.f};

    // ---- Pass A: row sums (K staged in LDS per panel) ----
    for (int p = 0; p < NPANEL; p++) {
        const int j0 = p * PANEL;
        #pragma unroll
        for (int it = 0; it < 8; it++) {           // stage K panel: 128x64 fp32->bf16
            const int idx = it * NTHR + tid;
            const int row = idx >> 4, c4 = idx & 15;
            float4 kv = *(const float4*)(Kb + (size_t)(j0 + row) * DIM + c4 * 4);
            *(short4*)(sK + row * PROWK + c4 * 4) =
                make_short4(f2bf(kv.x), f2bf(kv.y), f2bf(kv.z), f2bf(kv.w));
        }
        if (tid < PANEL) sMask[tid] = Mb[j0 + tid] ? 0.f : 1.f;
        __syncthreads();
        #pragma unroll
        for (int jt = 0; jt < 8; jt++) {
            const short* kr = sK + (jt * 16 + c) * PROWK + g * 8;
            bf16x8 kb0 = *(const bf16x8*)(kr);
            bf16x8 kb1 = *(const bf16x8*)(kr + 32);
            f32x4 acc = {0.f, 0.f, 0.f, 0.f};
            acc = __builtin_amdgcn_mfma_f32_16x16x32_bf16(qa0, kb0, acc, 0, 0, 0);
            acc = __builtin_amdgcn_mfma_f32_16x16x32_bf16(qa1, kb1, acc, 0, 0, 0);
            const float em = sMask[jt * 16 + c];
            #pragma unroll
            for (int r = 0; r < 4; r++)
                rsum[r] += __expf(acc[r] * scl) * em;
        }
        __syncthreads();
    }
    // reduce over the 16 lanes of each quad group (rows g*4+r wave-local)
    #pragma unroll
    for (int off = 1; off < 16; off <<= 1) {
        #pragma unroll
        for (int r = 0; r < 4; r++)
            rsum[r] += __shfl_xor(rsum[r], off, 64);
    }
    float scv[4];
    #pragma unroll
    for (int r = 0; r < 4; r++) {
        const int rm = Mb[i0w + g * 4 + r];
        scv[r] = (rm || rsum[r] <= 0.f) ? 0.f : 1.f / rsum[r];
    }

    // ---- Pass B: recompute, stage P, write attn, accumulate PV ----
    short* sPw = sP + w * 16 * PROWP;
    f32x4 pv[4];
    #pragma unroll
    for (int nt = 0; nt < 4; nt++) pv[nt] = (f32x4){0.f, 0.f, 0.f, 0.f};

    for (int p = 0; p < NPANEL; p++) {
        const int j0 = p * PANEL;
        #pragma unroll
        for (int it = 0; it < 8; it++) {           // stage K panel
            const int idx = it * NTHR + tid;
            const int row = idx >> 4, c4 = idx & 15;
            float4 kv = *(const float4*)(Kb + (size_t)(j0 + row) * DIM + c4 * 4);
            *(short4*)(sK + row * PROWK + c4 * 4) =
                make_short4(f2bf(kv.x), f2bf(kv.y), f2bf(kv.z), f2bf(kv.w));
        }
        #pragma unroll
        for (int it = 0; it < 2; it++) {           // stage V^T (4k x 4d reg transpose)
            const int task = it * NTHR + tid;
            const int k4 = task >> 4, d4g = task & 15;
            const int kb = k4 * 4, d4 = d4g * 4;
            const int colb = kb ^ ((d4g & 3) << 3);   // XOR swizzle (bank spread)
            const float* vp = Vb + (size_t)(j0 + kb) * DIM + d4;
            float4 r0 = *(const float4*)(vp);
            float4 r1 = *(const float4*)(vp + DIM);
            float4 r2 = *(const float4*)(vp + 2 * DIM);
            float4 r3 = *(const float4*)(vp + 3 * DIM);
            *(short4*)(sVT + (d4 + 0) * PROWV + colb) =
                make_short4(f2bf(r0.x), f2bf(r1.x), f2bf(r2.x), f2bf(r3.x));
            *(short4*)(sVT + (d4 + 1) * PROWV + colb) =
                make_short4(f2bf(r0.y), f2bf(r1.y), f2bf(r2.y), f2bf(r3.y));
            *(short4*)(sVT + (d4 + 2) * PROWV + colb) =
                make_short4(f2bf(r0.z), f2bf(r1.z), f2bf(r2.z), f2bf(r3.z));
            *(short4*)(sVT + (d4 + 3) * PROWV + colb) =
                make_short4(f2bf(r0.w), f2bf(r1.w), f2bf(r2.w), f2bf(r3.w));
        }
        if (tid < PANEL) sMask[tid] = Mb[j0 + tid] ? 0.f : 1.f;
        __syncthreads();

        // recompute P tiles -> per-wave bf16 panel (normalized)
        #pragma unroll
        for (int jt = 0; jt < 8; jt++) {
            const short* kr = sK + (jt * 16 + c) * PROWK + g * 8;
            bf16x8 kb0 = *(const bf16x8*)(kr);
            bf16x8 kb1 = *(const bf16x8*)(kr + 32);
            f32x4 acc = {0.f, 0.f, 0.f, 0.f};
            acc = __builtin_amdgcn_mfma_f32_16x16x32_bf16(qa0, kb0, acc, 0, 0, 0);
            acc = __builtin_amdgcn_mfma_f32_16x16x32_bf16(qa1, kb1, acc, 0, 0, 0);
            const float em = sMask[jt * 16 + c];
            #pragma unroll
            for (int r = 0; r < 4; r++)
                sPw[(g * 4 + r) * PROWP + jt * 16 + c] =
                    f2bf(__expf(acc[r] * scl) * em * scv[r]);
        }

        // PV: A-frag = ds_read_b128 from own P panel; B-frag = b128 from V^T
        #pragma unroll
        for (int ks = 0; ks < 4; ks++) {
            bf16x8 af = *(const bf16x8*)(sPw + c * PROWP + ks * 32 + g * 8);
            #pragma unroll
            for (int nt = 0; nt < 4; nt++) {
                const int d = nt * 16 + c;
                const int gp = g ^ ((d >> 2) & 3);
                bf16x8 bfrag = *(const bf16x8*)(sVT + d * PROWV + ks * 32 + gp * 8);
                pv[nt] = __builtin_amdgcn_mfma_f32_16x16x32_bf16(af, bfrag, pv[nt], 0, 0, 0);
            }
        }

        // attn write: 16 rows x 32 float4, fully coalesced (512B/half-wave)
        const size_t rowBase = (size_t)b * SLEN + i0w;
        #pragma unroll
        for (int it = 0; it < 8; it++) {
            const int idx = it * 64 + l;
            const int row = idx >> 5, col4 = idx & 31;
            const unsigned short* pp = (const unsigned short*)sPw + row * PROWP + col4 * 4;
            ushort4 p4 = *(const ushort4*)(pp);
            float4 o = {bf2f(p4.x), bf2f(p4.y), bf2f(p4.z), bf2f(p4.w)};
            *(float4*)(outAttn + (rowBase + row) * SLEN + j0 + col4 * 4) = o;
        }
        __syncthreads();   // protect sK/sVT/sMask/sP before next panel staging
    }

    // ctx write: C-layout direct store (pre-normalized P => no further scale)
    #pragma unroll
    for (int nt = 0; nt < 4; nt++) {
        #pragma unroll
        for (int r = 0; r < 4; r++)
            outCtx[((size_t)b * SLEN + i0w + g * 4 + r) * DIM + nt * 16 + c] = pv[nt][r];
    }
}

extern "C" void kernel_launch(void* const* d_in, const int* in_sizes, int n_in,
                              void* d_out, int out_size, void* d_ws, size_t ws_size,
                              hipStream_t stream) {
    const float* Q = (const float*)d_in[0];
    const float* K = (const float*)d_in[1];
    const float* V = (const float*)d_in[2];
    const int*   M = (const int*)d_in[3];
    float* outCtx  = (float*)d_out;
    float* outAttn = (float*)d_out + (size_t)NBATCH * SLEN * DIM;
    dim3 grid(NBATCH * (SLEN / TQ));   // 512 blocks
    sdpa_kernel<<<grid, NTHR, 0, stream>>>(Q, K, V, M, outCtx, outAttn);
}